// Round 11
// baseline (207.737 us; speedup 1.0000x reference)
//
#include <hip/hip_runtime.h>

#define B_ 32
#define C_ 80
#define T_ 2048
#define W_ 128
#define H_ 512
#define K_ 5

#define KTOT 400          // C_*K_
#define NKI  13           // K iterations of 32 (2 x 32x32x16 MFMA per iter)
#define TM   128
#define TN   128
#define SF_STRIDE 88      // f16 units
#define SF_ROWS   136     // 128 + 4 halo + slack (padded-K A reads stay in-bounds)
#define BF_ELEMS  (4 * NKI * 2 * 2 * 2 * 64 * 8)   // [nt][it][h][w2][j][lane][8] = 212992

// prep_all block-role boundaries
#define RB_FEAT   1024                             // feat transpose blocks
#define RB_BFRAG  (RB_FEAT + BF_ELEMS / 256)       // +832 = 1856
#define RB_WORDS  (RB_BFRAG + B_)                  // +32  = 1888
#define RB_WZERO  (RB_WORDS + 128)                 // +128 = 2016 (wemb zero)

typedef _Float16 half8 __attribute__((ext_vector_type(8)));
typedef float    f4v   __attribute__((ext_vector_type(4)));
typedef float    f16v  __attribute__((ext_vector_type(16)));

// ---------------------------------------------------------------------------
// prep_all: one dispatch, four roles by blockIdx.x.
// Bf layout now matches 32x32x16 wave fragments:
//   idx = ((((nt*13+it)*2+h)*2+w2)*2+j)*64*8 + lane*8 + e
//   n = nt*128 + w2*64 + j*32 + (lane&31), kc = it*32 + h*16 + (lane>>5)*8 + e
//   B[n][kc] = enc_w[(n*C + kc%80)*K + kc/80], zero for kc >= 400.
// ---------------------------------------------------------------------------
__global__ __launch_bounds__(256) void prep_all(
    const float* __restrict__ feat, const float* __restrict__ enc_w,
    const int* __restrict__ bounds, const int* __restrict__ lengths,
    _Float16* __restrict__ featT, _Float16* __restrict__ Bf,
    int* __restrict__ word_of, float* __restrict__ inv_cnt,
    float* __restrict__ wemb)
{
    __shared__ _Float16 tile[64 * 80];
    const int bid = blockIdx.x;
    const int tid = threadIdx.x;

    if (bid < RB_FEAT) {
        const int b = bid >> 5, tc = bid & 31;
        const int t0 = tc * 64;
        for (int idx = tid; idx < 80 * 64; idx += 256) {
            int cc = idx >> 6, tt = idx & 63;                  // coalesced over tt
            float v = feat[((size_t)b * C_ + cc) * T_ + t0 + tt];
            tile[tt * 80 + cc] = (_Float16)v;
        }
        __syncthreads();
        for (int idx = tid; idx < 64 * 10; idx += 256) {
            int tt = idx / 10, g = idx % 10;                   // coalesced writes
            *(f4v*)(featT + ((size_t)b * T_ + t0 + tt) * C_ + g * 8) =
                *(const f4v*)(tile + tt * 80 + g * 8);
        }
    } else if (bid < RB_BFRAG) {
        int idx = (bid - RB_FEAT) * 256 + tid;                 // < BF_ELEMS exactly
        int e  = idx & 7;
        int l  = (idx >> 3) & 63;
        int j  = (idx >> 9) & 1;
        int w2 = (idx >> 10) & 1;
        int h  = (idx >> 11) & 1;
        int it = (idx >> 12) % NKI;
        int nt = idx / (NKI << 12);
        int n  = nt * 128 + w2 * 64 + j * 32 + (l & 31);
        int kc = it * 32 + h * 16 + (l >> 5) * 8 + e;
        float v = 0.f;
        if (kc < KTOT) v = enc_w[(n * C_ + kc % 80) * K_ + kc / 80];
        Bf[idx] = (_Float16)v;
    } else if (bid < RB_WORDS) {
        const int b = bid - RB_BFRAG;
        int* wob = word_of + b * T_;
        for (int t = tid; t < T_; t += 256) wob[t] = -1;
        __syncthreads();
        if (tid < W_) {
            const int len = lengths[b];
            int s = bounds[(b * 2 + 0) * W_ + tid];
            int e = bounds[(b * 2 + 1) * W_ + tid];
            s = max(s, 0); e = min(e, T_);
            bool valid = (tid < len) && (e > s);
            inv_cnt[b * W_ + tid] = valid ? 1.f / (float)(e - s) : 0.f;
            if (valid)
                for (int t = s; t < e; ++t) wob[t] = tid;      // disjoint words
        }
    } else {
        f4v* wz = (f4v*)wemb;
        int base = (bid - RB_WORDS) * 256 + tid;
        for (int i = base; i < (B_ * W_ * H_) / 4; i += 128 * 256) wz[i] = (f4v){};
    }
}

// ---------------------------------------------------------------------------
// Implicit-GEMM conv + bias + ReLU + word mean-pool into wemb.
// Round-11: 32x32x16 f16 MFMA (higher rate, half the instructions, epilogue-
// friendly C layout) + persistent nt-loop: 512 blocks (2/CU uniform), A tile
// staged ONCE, all 4 nt B-slices processed against it. Barrier-free K-loops.
// Wave = 64m x 64n via 2x2 frags of 32x32; acc = 2x2 x f32x16 = 64 VGPRs.
// ---------------------------------------------------------------------------
__global__ __launch_bounds__(256, 3) void gemm_enc(
    const _Float16* __restrict__ featT,   // (B,T,C)
    const _Float16* __restrict__ Bf,      // wave-order fragments
    const float*    __restrict__ enc_b,   // (H)
    const int*      __restrict__ word_of, // (B,T)
    const float*    __restrict__ inv_cnt, // (B,W)
    float*          __restrict__ wemb)    // (B,W,H) pre-zeroed
{
    __shared__ _Float16 sf[SF_ROWS * SF_STRIDE];   // 23.9 KB

    const int tid = threadIdx.x;
    const int bid = blockIdx.x;
    const int mt = bid & 15;
    const int b  = bid >> 4;
    const int t0 = mt * TM;

    // ---- stage A tile once (rows tt: t = t0-2+tt, zero outside [0,T)) ----
    const _Float16* fb = featT + (size_t)b * T_ * C_;
    for (int idx = tid; idx < SF_ROWS * 10; idx += 256) {
        int tt = idx / 10, g = idx % 10;
        int t = t0 - 2 + tt;
        int tcl = min(max(t, 0), T_ - 1);
        f4v v = {};
        if (t >= 0 && t < T_) v = *(const f4v*)(fb + tcl * C_ + g * 8);
        *(f4v*)(sf + tt * SF_STRIDE + g * 8) = v;
    }

    const int lane = tid & 63;
    const int wid  = tid >> 6;
    const int wm  = (wid >> 1) * 64;     // wave m-base within tile
    const int wn0 = (wid & 1) * 64;      // wave n-base within 128-slice
    const int w2  = wid & 1;
    const int l31 = lane & 31;
    const int ls  = lane >> 5;
    const int q8  = ls * 8;

    // ---- word-group scalars (4 x 16-frame groups per wave; nt-invariant) ----
    const int bT = b * T_;
    const int bW = b * W_;
    int wlo[4], whi[4];
    #pragma unroll
    for (int g = 0; g < 4; ++g) {
        const int tg = t0 + wm + g * 16;
        wlo[g] = word_of[bT + tg];
        whi[g] = word_of[bT + tg + 15];
    }

    __syncthreads();   // sf ready; barrier-free from here on

    const int rowbase = (wm + l31) * SF_STRIDE;
    const half8* bfw = (const half8*)Bf + w2 * 128 + lane;   // wave/lane base

    for (int nt = 0; nt < 4; ++nt) {
        const half8* bptr = bfw + nt * (NKI * 512);
        const int h0 = nt * TN;

        f16v acc[2][2] = {};
        int c0 = q8,       off0 = q8;          // h=0 K-half tracker
        int c1 = 16 + q8,  off1 = 16 + q8;     // h=1 K-half tracker

        #pragma unroll
        for (int it = 0; it < NKI; ++it) {
            half8 a0[2], a1[2], b0[2], b1[2];
            #pragma unroll
            for (int i = 0; i < 2; ++i) {
                a0[i] = *(const half8*)(sf + rowbase + i * 32 * SF_STRIDE + off0);
                a1[i] = *(const half8*)(sf + rowbase + i * 32 * SF_STRIDE + off1);
            }
            #pragma unroll
            for (int j = 0; j < 2; ++j) {
                b0[j] = bptr[it * 512 + j * 64];
                b1[j] = bptr[it * 512 + 256 + j * 64];
            }
            #pragma unroll
            for (int i = 0; i < 2; ++i)
                #pragma unroll
                for (int j = 0; j < 2; ++j) {
                    acc[i][j] = __builtin_amdgcn_mfma_f32_32x32x16_f16(a0[i], b0[j], acc[i][j], 0, 0, 0);
                    acc[i][j] = __builtin_amdgcn_mfma_f32_32x32x16_f16(a1[i], b1[j], acc[i][j], 0, 0, 0);
                }
            c0 += 32; off0 += 32; if (c0 >= 80) { c0 -= 80; off0 += 8; }
            c1 += 32; off1 += 32; if (c1 >= 80) { c1 -= 80; off1 += 8; }
        }

        // ---- epilogue for this nt: bias + ReLU + mean-pool ----
        float bias[2];
        #pragma unroll
        for (int j = 0; j < 2; ++j) bias[j] = enc_b[h0 + wn0 + j * 32 + l31];

        #pragma unroll
        for (int i = 0; i < 2; ++i) {
            #pragma unroll
            for (int h16 = 0; h16 < 2; ++h16) {
                const int g = i * 2 + h16;
                const int tg = t0 + wm + i * 32 + h16 * 16;
                const int w0 = wlo[g], w15 = whi[g];
                if (w0 == w15) {
                    if (w0 >= 0) {
                        const float inv = inv_cnt[bW + w0];
                        const bool own_lo = (tg == 0) || (word_of[bT + tg - 1] != w0);
                        const bool own_hi = (tg + 16 >= T_) || (word_of[bT + tg + 16] != w0);
                        #pragma unroll
                        for (int j = 0; j < 2; ++j) {
                            float s = 0.f;
                            #pragma unroll
                            for (int r = 0; r < 8; ++r)
                                s += fmaxf(acc[i][j][h16 * 8 + r] + bias[j], 0.f);
                            s += __shfl_down(s, 32, 64);       // fold ls=1 into ls=0
                            if (lane < 32) {
                                float val = s * inv;
                                float* dst = &wemb[(size_t)(bW + w0) * H_ + h0 + wn0 + j * 32 + lane];
                                if (own_lo && own_hi) *dst = val;   // sole owner
                                else atomicAdd(dst, val);
                            }
                        }
                    }
                } else {   // general path: rows of this group span words
                    #pragma unroll
                    for (int j = 0; j < 2; ++j) {
                        #pragma unroll
                        for (int r = 0; r < 8; ++r) {
                            const int reg = h16 * 8 + r;
                            const int row = (reg & 3) + 8 * (reg >> 2) + 4 * ls;
                            const int t = t0 + wm + i * 32 + row;
                            const int w = word_of[bT + t];
                            if (w >= 0)
                                atomicAdd(&wemb[(size_t)(bW + w) * H_ + h0 + wn0 + j * 32 + l31],
                                          fmaxf(acc[i][j][reg] + bias[j], 0.f) * inv_cnt[bW + w]);
                        }
                    }
                }
            }
        }
    }
}

// ---------------------------------------------------------------------------
// Decoder, single dispatch (unchanged)
// ---------------------------------------------------------------------------
__global__ __launch_bounds__(256) void dec_all(const float* __restrict__ wemb,
                                               const float* __restrict__ dec_w,
                                               const float* __restrict__ dec_b,
                                               float* __restrict__ out) {
    __shared__ float sdw[H_ * K_];       // 10.2 KB
    __shared__ float se[36][8];          // e rows, k-stride 8
    const int bid = blockIdx.x;          // b*4 + ch
    const int b = bid >> 2, ch = bid & 3;
    const int w0 = ch * 32;
    for (int idx = threadIdx.x; idx < H_ * K_; idx += 256) sdw[idx] = dec_w[idx];
    __syncthreads();
    const int wid = threadIdx.x >> 6, lane = threadIdx.x & 63;
    for (int row = wid; row < 36; row += 4) {
        int wq = w0 - 2 + row;
        float a[K_] = {};
        if (wq >= 0 && wq < W_) {
            const float* src = wemb + ((size_t)b * W_ + wq) * H_;
            #pragma unroll
            for (int r = 0; r < H_ / 64; ++r) {
                int h = r * 64 + lane;
                float v = src[h];
                #pragma unroll
                for (int k = 0; k < K_; ++k) a[k] += v * sdw[h * K_ + k];
            }
        }
        #pragma unroll
        for (int k = 0; k < K_; ++k) {
            #pragma unroll
            for (int off = 32; off > 0; off >>= 1) a[k] += __shfl_down(a[k], off, 64);
        }
        if (lane == 0) {
            #pragma unroll
            for (int k = 0; k < K_; ++k) se[row][k] = a[k];
        }
    }
    __syncthreads();
    if (threadIdx.x < 32) {
        int wl = threadIdx.x;
        float acc = dec_b[0];
        #pragma unroll
        for (int k = 0; k < K_; ++k) acc += se[wl + k][k];
        out[b * W_ + w0 + wl] = acc;
    }
}

// ---------------------------------------------------------------------------
extern "C" void kernel_launch(void* const* d_in, const int* in_sizes, int n_in,
                              void* d_out, int out_size, void* d_ws, size_t ws_size,
                              hipStream_t stream) {
    const float* feat    = (const float*)d_in[0];
    const int*   bounds  = (const int*)  d_in[1];
    const int*   lengths = (const int*)  d_in[2];
    const float* enc_w   = (const float*)d_in[3];
    const float* enc_b   = (const float*)d_in[4];
    const float* dec_w   = (const float*)d_in[5];
    const float* dec_b   = (const float*)d_in[6];
    float* out = (float*)d_out;

    char* p = (char*)d_ws;
    _Float16* featT = (_Float16*)p;  p += (size_t)B_ * T_ * C_ * 2;       // 10.49 MB
    _Float16* Bf    = (_Float16*)p;  p += (size_t)BF_ELEMS * 2;           // 0.43 MB
    int* word_of    = (int*)p;       p += (size_t)B_ * T_ * 4;            // 0.26 MB
    float* inv_cnt  = (float*)p;     p += (size_t)B_ * W_ * 4;            // 16 KB
    float* wemb     = (float*)p;                                          // 8.39 MB

    prep_all<<<RB_WZERO, 256, 0, stream>>>(feat, enc_w, bounds, lengths,
                                           featT, Bf, word_of, inv_cnt, wemb);
    gemm_enc<<<B_ * (T_ / TM), 256, 0, stream>>>(
        featT, Bf, enc_b, word_of, inv_cnt, wemb);
    dec_all<<<B_ * 4, 256, 0, stream>>>(wemb, dec_w, dec_b, out);
}

// Round 12
// 123.378 us; speedup vs baseline: 1.6838x; 1.6838x over previous
//
#include <hip/hip_runtime.h>

#define B_ 32
#define C_ 80
#define T_ 2048
#define W_ 128
#define H_ 512
#define K_ 5

#define KTOT 400          // C_*K_
#define NKI  13           // K iterations of 32
#define TM   128
#define TN   128
#define SF_STRIDE 80      // == C_: makes staging + A addressing exactly linear
#define SF_ROWS   136     // 128 + 4 halo + slack; 136*80 f16 = 21760 B
#define SF_ELEMS  (SF_ROWS * SF_STRIDE)
#define ITER_STRIDE (2 * 4 * 64 * 8)               // Bf elems per K-iter per nt
#define BF_ELEMS  (4 * NKI * ITER_STRIDE)          // [nt][it][w2][j][lane][8] = 212992

// prep_all block-role boundaries
#define RB_FEAT   1024                             // feat transpose blocks
#define RB_BFRAG  (RB_FEAT + BF_ELEMS / 256)       // +832 = 1856
#define RB_WORDS  (RB_BFRAG + B_)                  // +32  = 1888
#define RB_WZERO  (RB_WORDS + 128)                 // +128 = 2016 (wemb zero)

typedef _Float16 half8 __attribute__((ext_vector_type(8)));
typedef float    f4v   __attribute__((ext_vector_type(4)));

typedef const __attribute__((address_space(1))) unsigned int guint;
typedef __attribute__((address_space(3))) unsigned int luint;

// ---------------------------------------------------------------------------
// prep_all: one dispatch, four roles by blockIdx.x (round-8 version: Bf in
// 16x16x32 wave-fragment order)
// ---------------------------------------------------------------------------
__global__ __launch_bounds__(256) void prep_all(
    const float* __restrict__ feat, const float* __restrict__ enc_w,
    const int* __restrict__ bounds, const int* __restrict__ lengths,
    _Float16* __restrict__ featT, _Float16* __restrict__ Bf,
    int* __restrict__ word_of, float* __restrict__ inv_cnt,
    float* __restrict__ wemb)
{
    __shared__ _Float16 tile[64 * 80];
    const int bid = blockIdx.x;
    const int tid = threadIdx.x;

    if (bid < RB_FEAT) {
        const int b = bid >> 5, tc = bid & 31;
        const int t0 = tc * 64;
        for (int idx = tid; idx < 80 * 64; idx += 256) {
            int cc = idx >> 6, tt = idx & 63;                  // coalesced over tt
            float v = feat[((size_t)b * C_ + cc) * T_ + t0 + tt];
            tile[tt * 80 + cc] = (_Float16)v;
        }
        __syncthreads();
        for (int idx = tid; idx < 64 * 10; idx += 256) {
            int tt = idx / 10, g = idx % 10;                   // coalesced writes
            *(f4v*)(featT + ((size_t)b * T_ + t0 + tt) * C_ + g * 8) =
                *(const f4v*)(tile + tt * 80 + g * 8);
        }
    } else if (bid < RB_BFRAG) {
        int idx = (bid - RB_FEAT) * 256 + tid;                 // < BF_ELEMS exactly
        int e  = idx & 7;
        int l  = (idx >> 3) & 63;
        int j  = (idx >> 9) & 3;
        int w2 = (idx >> 11) & 1;
        int it = (idx >> 12) % NKI;
        int nt = idx / (NKI << 12);
        int h  = nt * 128 + w2 * 64 + j * 16 + (l & 15);
        int kc = it * 32 + (l >> 4) * 8 + e;
        float v = 0.f;
        if (kc < KTOT) v = enc_w[(h * C_ + kc % 80) * K_ + kc / 80];
        Bf[idx] = (_Float16)v;
    } else if (bid < RB_WORDS) {
        const int b = bid - RB_BFRAG;
        int* wob = word_of + b * T_;
        for (int t = tid; t < T_; t += 256) wob[t] = -1;
        __syncthreads();
        if (tid < W_) {
            const int len = lengths[b];
            int s = bounds[(b * 2 + 0) * W_ + tid];
            int e = bounds[(b * 2 + 1) * W_ + tid];
            s = max(s, 0); e = min(e, T_);
            bool valid = (tid < len) && (e > s);
            inv_cnt[b * W_ + tid] = valid ? 1.f / (float)(e - s) : 0.f;
            if (valid)
                for (int t = s; t < e; ++t) wob[t] = tid;      // disjoint words
        }
    } else {
        f4v* wz = (f4v*)wemb;
        int base = (bid - RB_WORDS) * 256 + tid;
        for (int i = base; i < (B_ * W_ * H_) / 4; i += 128 * 256) wz[i] = (f4v){};
    }
}

// ---------------------------------------------------------------------------
// Implicit-GEMM conv (f16 MFMA) + bias + ReLU + word mean-pool into wemb.
// Round-12 = round-8 structure (best known) with A staging via
// global_load_lds width=16: SF_STRIDE==C makes both global src and LDS dst
// linear in lane*16B (wave-uniform-base requirement satisfied). SAME-pad
// boundary rows zeroed post-barrier in edge blocks. K-loop A addressing is
// now purely linear (row-advance +80 cancels column wrap -80).
// ---------------------------------------------------------------------------
__global__ __launch_bounds__(256, 3) void gemm_enc(
    const _Float16* __restrict__ featT,   // (B,T,C)
    const _Float16* __restrict__ Bf,      // wave-order fragments (padded +2 iters)
    const float*    __restrict__ enc_b,   // (H)
    const int*      __restrict__ word_of, // (B,T)
    const float*    __restrict__ inv_cnt, // (B,W)
    float*          __restrict__ wemb)    // (B,W,H) pre-zeroed
{
    __shared__ __attribute__((aligned(16))) _Float16 sf[SF_ELEMS];   // 21.25 KB

    const int tid = threadIdx.x;
    const int bid = blockIdx.x;
    const int nt = bid & 3;          // nt in low bits: per-XCD Bf slice residency
    const int mt = (bid >> 2) & 15;
    const int b  = bid >> 6;
    const int t0 = mt * TM;
    const int h0 = nt * TN;

    const int lane = tid & 63;
    const int wid  = tid >> 6;
    const int wm = (wid >> 1) * 64;
    const int wn = (wid & 1) * 64;
    const int w2 = wid & 1;
    const int ml = lane & 15;
    const int q  = lane >> 4;

    // ---- stage A tile via global_load_lds (16 B/lane, linear both sides) ----
    // sf f16 offset loff = ch*512 + lane*8  <->  global f16 offset fbase + loff
    {
        const _Float16* fb = featT + (size_t)b * T_ * C_;
        const int fbase = (t0 - 2) * C_;                 // may be <0 (mt==0)
        const int gmax  = T_ * C_ - 8;                   // clamp; garbage re-zeroed
        for (int ch = wid; ch < 22; ch += 4) {           // 21 full + 1 tail chunk
            int loff = (ch << 9) + lane * 8;
            if (loff < SF_ELEMS) {                       // tail: lanes >=16 masked
                int goff = fbase + loff;
                goff = min(max(goff, 0), gmax);
                __builtin_amdgcn_global_load_lds((guint*)(fb + goff),
                                                 (luint*)(sf + (ch << 9)), 16, 0, 0);
            }
        }
    }

    // ---- epilogue scalar prefetch (independent of staging/K-loop) ----
    const int bT = b * T_;
    const int bW = b * W_;
    int wlo[4], whi[4];
    #pragma unroll
    for (int i = 0; i < 4; ++i) {
        const int tg = t0 + wm + i * 16;
        wlo[i] = word_of[bT + tg];
        whi[i] = word_of[bT + tg + 15];
    }

    __syncthreads();   // drains global_load_lds (vmcnt) + barrier

    // SAME-pad rows outside [0,T) hold clamp-garbage in edge blocks: zero them.
    if (mt == 0) {                       // rows 0,1 (t=-2,-1): 160 f16 = 20 f4v
        if (tid < 20) ((f4v*)sf)[tid] = (f4v){};
        __syncthreads();
    }
    if (mt == 15) {                      // rows 130..135 (t>=2048): 60 f4v
        if (tid < 60) ((f4v*)(sf + 130 * SF_STRIDE))[tid] = (f4v){};
        __syncthreads();
    }

    // B fragment stream base; iter stride = 512 half8
    const half8* bfp = (const half8*)(Bf + (((nt * NKI) * 2 + w2) * 4 * 64 + lane) * 8);

    f4v acc[4][4] = {};

    // A addressing is linear: af(it,i) = sf + abase + it*32 + i*16*80
    const int abase = (wm + ml) * SF_STRIDE + q * 8;

    // preload: A(it0); B(it0), B(it1)
    half8 acur[4], bcur[4], bnxt[4];
    #pragma unroll
    for (int i = 0; i < 4; ++i)
        acur[i] = *(const half8*)(sf + abase + i * 16 * SF_STRIDE);
    #pragma unroll
    for (int j = 0; j < 4; ++j) bcur[j] = bfp[j * 64];
    #pragma unroll
    for (int j = 0; j < 4; ++j) bnxt[j] = bfp[512 + j * 64];

    #pragma unroll
    for (int it = 0; it < NKI; ++it) {
        half8 anxt[4], bnn[4];
        #pragma unroll
        for (int i = 0; i < 4; ++i)      // A(it+1); max offset < SF_ELEMS (slack)
            anxt[i] = *(const half8*)(sf + abase + (it + 1) * 32 + i * 16 * SF_STRIDE);
        {                                // B(it+2); Bf padded +2 iters
            const half8* bn = bfp + (it + 2) * 512;
            #pragma unroll
            for (int j = 0; j < 4; ++j) bnn[j] = bn[j * 64];
        }
        #pragma unroll
        for (int i = 0; i < 4; ++i)
            #pragma unroll
            for (int j = 0; j < 4; ++j)
                acc[i][j] = __builtin_amdgcn_mfma_f32_16x16x32_f16(acur[i], bcur[j], acc[i][j], 0, 0, 0);
        #pragma unroll
        for (int i = 0; i < 4; ++i) acur[i] = anxt[i];
        #pragma unroll
        for (int j = 0; j < 4; ++j) { bcur[j] = bnxt[j]; bnxt[j] = bnn[j]; }
    }

    // ---- epilogue: bias + ReLU + mean-pool ----
    float bias[4];
    #pragma unroll
    for (int j = 0; j < 4; ++j) bias[j] = enc_b[h0 + wn + j * 16 + ml];

    #pragma unroll
    for (int i = 0; i < 4; ++i) {
        const int tg = t0 + wm + i * 16;
        const int w0  = wlo[i];
        const int w15 = whi[i];
        if (w0 == w15) {
            if (w0 >= 0) {
                const float inv = inv_cnt[bW + w0];
                const bool own_lo = (tg == 0) || (word_of[bT + tg - 1] != w0);
                const bool own_hi = (tg + 16 >= T_) || (word_of[bT + tg + 16] != w0);
                #pragma unroll
                for (int j = 0; j < 4; ++j) {
                    float s = 0.f;
                    #pragma unroll
                    for (int r = 0; r < 4; ++r) s += fmaxf(acc[i][j][r] + bias[j], 0.f);
                    s += __shfl_down(s, 32, 64);
                    s += __shfl_down(s, 16, 64);
                    if (q == 0) {
                        float val = s * inv;
                        float* dst = &wemb[(size_t)(bW + w0) * H_ + h0 + wn + j * 16 + ml];
                        if (own_lo && own_hi) *dst = val;       // sole owner
                        else atomicAdd(dst, val);
                    }
                }
            }
        } else {
            #pragma unroll
            for (int j = 0; j < 4; ++j) {
                #pragma unroll
                for (int r = 0; r < 4; ++r) {
                    int t = tg + q * 4 + r;
                    int w = word_of[bT + t];
                    if (w >= 0)
                        atomicAdd(&wemb[(size_t)(bW + w) * H_ + h0 + wn + j * 16 + ml],
                                  fmaxf(acc[i][j][r] + bias[j], 0.f) * inv_cnt[bW + w]);
                }
            }
        }
    }
}

// ---------------------------------------------------------------------------
// Decoder, single dispatch (unchanged)
// ---------------------------------------------------------------------------
__global__ __launch_bounds__(256) void dec_all(const float* __restrict__ wemb,
                                               const float* __restrict__ dec_w,
                                               const float* __restrict__ dec_b,
                                               float* __restrict__ out) {
    __shared__ float sdw[H_ * K_];       // 10.2 KB
    __shared__ float se[36][8];          // e rows, k-stride 8
    const int bid = blockIdx.x;          // b*4 + ch
    const int b = bid >> 2, ch = bid & 3;
    const int w0 = ch * 32;
    for (int idx = threadIdx.x; idx < H_ * K_; idx += 256) sdw[idx] = dec_w[idx];
    __syncthreads();
    const int wid = threadIdx.x >> 6, lane = threadIdx.x & 63;
    for (int row = wid; row < 36; row += 4) {
        int wq = w0 - 2 + row;
        float a[K_] = {};
        if (wq >= 0 && wq < W_) {
            const float* src = wemb + ((size_t)b * W_ + wq) * H_;
            #pragma unroll
            for (int r = 0; r < H_ / 64; ++r) {
                int h = r * 64 + lane;
                float v = src[h];
                #pragma unroll
                for (int k = 0; k < K_; ++k) a[k] += v * sdw[h * K_ + k];
            }
        }
        #pragma unroll
        for (int k = 0; k < K_; ++k) {
            #pragma unroll
            for (int off = 32; off > 0; off >>= 1) a[k] += __shfl_down(a[k], off, 64);
        }
        if (lane == 0) {
            #pragma unroll
            for (int k = 0; k < K_; ++k) se[row][k] = a[k];
        }
    }
    __syncthreads();
    if (threadIdx.x < 32) {
        int wl = threadIdx.x;
        float acc = dec_b[0];
        #pragma unroll
        for (int k = 0; k < K_; ++k) acc += se[wl + k][k];
        out[b * W_ + w0 + wl] = acc;
    }
}

// ---------------------------------------------------------------------------
extern "C" void kernel_launch(void* const* d_in, const int* in_sizes, int n_in,
                              void* d_out, int out_size, void* d_ws, size_t ws_size,
                              hipStream_t stream) {
    const float* feat    = (const float*)d_in[0];
    const int*   bounds  = (const int*)  d_in[1];
    const int*   lengths = (const int*)  d_in[2];
    const float* enc_w   = (const float*)d_in[3];
    const float* enc_b   = (const float*)d_in[4];
    const float* dec_w   = (const float*)d_in[5];
    const float* dec_b   = (const float*)d_in[6];
    float* out = (float*)d_out;

    char* p = (char*)d_ws;
    _Float16* featT = (_Float16*)p;  p += (size_t)B_ * T_ * C_ * 2;                 // 10.49 MB
    _Float16* Bf    = (_Float16*)p;  p += (size_t)(BF_ELEMS + 2 * ITER_STRIDE) * 2; // 0.44 MB (+2-iter pad)
    int* word_of    = (int*)p;       p += (size_t)B_ * T_ * 4;                      // 0.26 MB
    float* inv_cnt  = (float*)p;     p += (size_t)B_ * W_ * 4;                      // 16 KB
    float* wemb     = (float*)p;                                                    // 8.39 MB

    prep_all<<<RB_WZERO, 256, 0, stream>>>(feat, enc_w, bounds, lengths,
                                           featT, Bf, word_of, inv_cnt, wemb);
    gemm_enc<<<B_ * (T_ / TM) * (H_ / TN), 256, 0, stream>>>(
        featT, Bf, enc_b, word_of, inv_cnt, wemb);
    dec_all<<<B_ * 4, 256, 0, stream>>>(wemb, dec_w, dec_b, out);
}